// Round 8
// baseline (188.792 us; speedup 1.0000x reference)
//
#include <hip/hip_runtime.h>

// ---------------------------------------------------------------------------
// SimpleVisionAttention on MI355X (gfx950)
// S=2048, DIM=1280 (16 heads x 80), fp32 in/out, f16 MFMA internally.
//
// Pipeline:
//   K1  fused cast fp32 -> f16   (hs, w_qkv, w_proj)
//   K2  QKV GEMM  128x128 tiles, 8 waves, BK=64 dual-panel. v7: DOUBLE-
//       BUFFERED LDS, STAGE(t+1) issued BEFORE compute(t), ONE barrier/iter
//       (T3 minimum-2-phase: the old {bar; GLD16; bar-drain; compute} loop
//       never overlapped the GLD16 flight with compute — m97's ~20% stall).
//   K3  fused RoPE + repack Qh/Kh [h][s][80] (dense) + V transpose -> Vt[h][d][s]
//   K4  flash attention (v6 schedule — v4/v5/v6 all within noise; kept as-is)
//   K4b combine 4 partials, half8-wide
//   K5  proj GEMM 64x128 tiles, v7: same 2-phase dbuf, (256,3) (48 KB LDS x3)
// ---------------------------------------------------------------------------

#define SEQLEN   2048
#define DIMM     1280
#define NHEADS   16
#define HD       80
#define QKV_N    3840
#define NSPLIT   4
#define KVSPAN   (SEQLEN / NSPLIT)
// SCALE * log2(e) folded into Q at rope time; softmax done in base-2.
#define QSCALE_LOG2E 0.16130083587064776f   // 80^-0.5 * 1.4426950408889634

#define KSTRIDE  88   // K-tile row stride (44 dw): 8-bank spread, 2-way = free
#define VFSTRIDE 24   // VF row stride (12 dw): balanced lane->bank spread

// device base-2 exp: v_exp_f32 (NOT __exp2f — collides with glibc math.h)
#define EXP2F(x) __builtin_amdgcn_exp2f(x)

// async global->LDS, 16B per lane; LDS dest must be waveBase + lane*16
#define GLD16(gptr, lptr)                                                      \
    __builtin_amdgcn_global_load_lds(                                          \
        (const __attribute__((address_space(1))) void*)(gptr),                 \
        (__attribute__((address_space(3))) void*)(lptr), 16, 0, 0)

typedef float f32x4 __attribute__((ext_vector_type(4)));
typedef _Float16 half8 __attribute__((ext_vector_type(8)));
typedef _Float16 half4 __attribute__((ext_vector_type(4)));
typedef _Float16 half2v __attribute__((ext_vector_type(2)));

static __device__ __forceinline__ f32x4 mfma_16x16x32(half8 a, half8 b, f32x4 c) {
    return __builtin_amdgcn_mfma_f32_16x16x32_f16(a, b, c, 0, 0, 0);
}
// NOTE: legacy K=16 shape is spelled WITHOUT the underscore: ...16x16x16f16
static __device__ __forceinline__ f32x4 mfma_16x16x16(half4 a, half4 b, f32x4 c) {
    return __builtin_amdgcn_mfma_f32_16x16x16f16(a, b, c, 0, 0, 0);
}
static __device__ __forceinline__ half4 lo4(half8 v) {
    return __builtin_shufflevector(v, v, 0, 1, 2, 3);
}
static __device__ __forceinline__ half4 hi4(half8 v) {
    return __builtin_shufflevector(v, v, 4, 5, 6, 7);
}

// ---------------------------------------------------------------------------
// One fused cast kernel for the three fp32->f16 conversions.
__global__ __launch_bounds__(256)
void cast_all(const float* __restrict__ hs, const float* __restrict__ wq,
              const float* __restrict__ wp, _Float16* __restrict__ dhs,
              _Float16* __restrict__ dwq, _Float16* __restrict__ dwp) {
    const int n1 = SEQLEN * DIMM / 4, n2 = QKV_N * DIMM / 4, n3 = DIMM * DIMM / 4;
    int i = blockIdx.x * 256 + threadIdx.x;
    const float4* src; half4* dst; int j;
    if (i < n1)           { src = (const float4*)hs; dst = (half4*)dhs; j = i; }
    else if (i < n1 + n2) { src = (const float4*)wq; dst = (half4*)dwq; j = i - n1; }
    else if (i < n1 + n2 + n3) { src = (const float4*)wp; dst = (half4*)dwp; j = i - n1 - n2; }
    else return;
    const float4 v = src[j];
    half4 h;
    h.x = (_Float16)v.x; h.y = (_Float16)v.y;
    h.z = (_Float16)v.z; h.w = (_Float16)v.w;
    dst[j] = h;
}

// ---------------------------------------------------------------------------
// 128x128 block tile, 8 waves 4x2 (each 32x64, 2x4 mfma tiles), BK=64 as two
// BK=32 panels. v7: double-buffered LDS + single barrier per K-iter; the
// STAGE for iter t+1 is issued before compute(t), so the 4 GLD16s fly under
// ~310 cy of MFMA and the barrier's vmcnt drain is ~free.
// LDS 64 KB -> 2 blocks/CU (128 KB <= 160 KB).
template<bool OUT_F16>
__global__ __launch_bounds__(512, 4)
void gemm_bt128(const _Float16* __restrict__ A, const _Float16* __restrict__ B,
                const float* __restrict__ bias, void* __restrict__ Cout,
                int M, int N, int K) {
    __shared__ __align__(16) _Float16 As[2][2][128 * 32];   // [buf][panel] 32 KB
    __shared__ __align__(16) _Float16 Bs[2][2][128 * 32];   // 32 KB
    const int tid  = threadIdx.x;
    const int lane = tid & 63;
    const int wave = tid >> 6;
    const int l15  = lane & 15;
    const int quad = lane >> 4;
    const int wm   = wave & 3;           // 4 row-waves of 32
    const int wn   = wave >> 2;          // 2 col-waves of 64
    const long bm = blockIdx.x, bn = blockIdx.y;

    const _Float16* Ag = A + bm * 128 * (long)K;
    const _Float16* Bg = B + bn * 128 * (long)K;

    const int srow = lane >> 2;            // 0..15 within wave's 16-row strip
    const int scol = (lane & 3) * 8;       // halves
    const long r   = 16 * wave + srow;     // 0..127 (this thread's stage row)
    f32x4 acc[2][4] = {};

    auto stage = [&](int b, int k0) {
#pragma unroll
        for (int p = 0; p < 2; p++) {
            const int kp = k0 + p * 32;
            GLD16(Ag + r * K + kp + scol, &As[b][p][512 * wave + lane * 8]);
            GLD16(Bg + r * K + kp + scol, &Bs[b][p][512 * wave + lane * 8]);
        }
    };

    stage(0, 0);
    __syncthreads();                       // drains prologue stage

    int cb = 0;
    for (int k0 = 0; k0 < K; k0 += 64) {
        if (k0 + 64 < K) stage(cb ^ 1, k0 + 64);   // flies under compute
#pragma unroll
        for (int p = 0; p < 2; p++) {
            half8 af[2], bf[4];
#pragma unroll
            for (int t = 0; t < 2; t++)
                af[t] = *(const half8*)&As[cb][p][(wm * 32 + t * 16 + l15) * 32 + quad * 8];
#pragma unroll
            for (int t = 0; t < 4; t++)
                bf[t] = *(const half8*)&Bs[cb][p][(wn * 64 + t * 16 + l15) * 32 + quad * 8];
#pragma unroll
            for (int mt = 0; mt < 2; mt++)
#pragma unroll
                for (int nt = 0; nt < 4; nt++)
                    acc[mt][nt] = mfma_16x16x32(af[mt], bf[nt], acc[mt][nt]);
        }
        __syncthreads();                   // drains stage(t+1); guards reuse
        cb ^= 1;
    }

    float bv[4];
#pragma unroll
    for (int nt = 0; nt < 4; nt++)
        bv[nt] = bias[bn * 128 + wn * 64 + nt * 16 + l15];

#pragma unroll
    for (int mt = 0; mt < 2; mt++) {
#pragma unroll
        for (int rr = 0; rr < 4; rr++) {
            const long row = bm * 128 + wm * 32 + mt * 16 + quad * 4 + rr;
#pragma unroll
            for (int nt = 0; nt < 4; nt++) {
                const long col = bn * 128 + wn * 64 + nt * 16 + l15;
                const float v = acc[mt][nt][rr] + bv[nt];
                if (OUT_F16) ((_Float16*)Cout)[row * (long)N + col] = (_Float16)v;
                else         ((float*)Cout)[row * (long)N + col] = v;
            }
        }
    }
}

// ---------------------------------------------------------------------------
// 64x128 tile, 4 waves (proj GEMM). v7: same 2-phase dbuf; 48 KB LDS at
// (256,3) -> 3 blocks/CU (144 KB <= 160 KB).
template<bool OUT_F16>
__global__ __launch_bounds__(256, 3)
void gemm_bt64(const _Float16* __restrict__ A, const _Float16* __restrict__ B,
               const float* __restrict__ bias, void* __restrict__ Cout,
               int M, int N, int K) {
    __shared__ __align__(16) _Float16 As[2][2][64 * 32];    // 16 KB
    __shared__ __align__(16) _Float16 Bs[2][2][128 * 32];   // 32 KB
    const int tid  = threadIdx.x;
    const int lane = tid & 63;
    const int wave = tid >> 6;
    const int l15  = lane & 15;
    const int quad = lane >> 4;
    const int wm   = wave & 1;
    const int wn   = wave >> 1;
    const long bm = blockIdx.x, bn = blockIdx.y;

    const _Float16* Ag = A + bm * 64 * (long)K;
    const _Float16* Bg = B + bn * 128 * (long)K;

    const int srow = lane >> 2;            // 0..15 within chunk
    const int scol = (lane & 3) * 8;       // halves
    f32x4 acc[2][4] = {};

    auto stage = [&](int b, int k0) {
#pragma unroll
        for (int p = 0; p < 2; p++) {
            const int kp = k0 + p * 32;
            const long arow = 16 * wave + srow;
            GLD16(Ag + arow * K + kp + scol, &As[b][p][512 * wave + lane * 8]);
#pragma unroll
            for (int cc = 0; cc < 2; cc++) {
                const int c = wave + cc * 4;
                const long brow = 16 * c + srow;
                GLD16(Bg + brow * K + kp + scol, &Bs[b][p][512 * c + lane * 8]);
            }
        }
    };

    stage(0, 0);
    __syncthreads();

    int cb = 0;
    for (int k0 = 0; k0 < K; k0 += 64) {
        if (k0 + 64 < K) stage(cb ^ 1, k0 + 64);
#pragma unroll
        for (int p = 0; p < 2; p++) {
            half8 af[2], bf[4];
#pragma unroll
            for (int t = 0; t < 2; t++)
                af[t] = *(const half8*)&As[cb][p][(wm * 32 + t * 16 + l15) * 32 + quad * 8];
#pragma unroll
            for (int t = 0; t < 4; t++)
                bf[t] = *(const half8*)&Bs[cb][p][(wn * 64 + t * 16 + l15) * 32 + quad * 8];
#pragma unroll
            for (int mt = 0; mt < 2; mt++)
#pragma unroll
                for (int nt = 0; nt < 4; nt++)
                    acc[mt][nt] = mfma_16x16x32(af[mt], bf[nt], acc[mt][nt]);
        }
        __syncthreads();
        cb ^= 1;
    }

    float bv[4];
#pragma unroll
    for (int nt = 0; nt < 4; nt++)
        bv[nt] = bias[bn * 128 + wn * 64 + nt * 16 + l15];

#pragma unroll
    for (int mt = 0; mt < 2; mt++) {
#pragma unroll
        for (int rr = 0; rr < 4; rr++) {
            const long row = bm * 64 + wm * 32 + mt * 16 + quad * 4 + rr;
#pragma unroll
            for (int nt = 0; nt < 4; nt++) {
                const long col = bn * 128 + wn * 64 + nt * 16 + l15;
                const float v = acc[mt][nt][rr] + bv[nt];
                if (OUT_F16) ((_Float16*)Cout)[row * (long)N + col] = (_Float16)v;
                else         ((float*)Cout)[row * (long)N + col] = v;
            }
        }
    }
}

// ---------------------------------------------------------------------------
// Fused: RoPE on q,k -> Qh/Kh [h][s][80] dense (Q pre-scaled by SCALE*log2e)
// + V transposed via LDS -> Vt[h][d][s]. Block = (64 seqs, 1 head).
__global__ __launch_bounds__(256)
void rope_repack_t(const _Float16* __restrict__ qkv,
                   const float* __restrict__ cosb,
                   const float* __restrict__ sinb,
                   _Float16* __restrict__ Qh,
                   _Float16* __restrict__ Kh,
                   _Float16* __restrict__ Vt) {
    const int s0 = blockIdx.x * 64;
    const int h  = blockIdx.y;
    __shared__ __align__(16) _Float16 Ts[64 * 88];
    const int tid = threadIdx.x;

    // stage V rows into LDS (transposed write later)
    for (int i = tid; i < 640; i += 256) {          // 64 rows x 10 chunks
        const int r = i / 10, c = (i - r * 10) * 8;
        *(half8*)&Ts[r * 88 + c] =
            *(const half8*)&qkv[(long)(s0 + r) * QKV_N + 2 * DIMM + h * HD + c];
    }

    // q,k rope: 64 rows x 5 chunks of 8 (d in [0,40))
    for (int i = tid; i < 320; i += 256) {
        const int r = i / 5, d = (i - r * 5) * 8;
        const _Float16* row = qkv + (long)(s0 + r) * QKV_N + h * HD;
        const half8 q0 = *(const half8*)&row[d];
        const half8 q1 = *(const half8*)&row[d + 40];
        const half8 k0 = *(const half8*)&row[DIMM + d];
        const half8 k1 = *(const half8*)&row[DIMM + d + 40];
        const float4 cA = *(const float4*)&cosb[(s0 + r) * HD + d];
        const float4 cB = *(const float4*)&cosb[(s0 + r) * HD + d + 4];
        const float4 sA = *(const float4*)&sinb[(s0 + r) * HD + d];
        const float4 sB = *(const float4*)&sinb[(s0 + r) * HD + d + 4];
        half8 qo0, qo1, ko0, ko1;
#pragma unroll
        for (int j = 0; j < 8; j++) {
            const float cj = (j < 4) ? cA[j] : cB[j - 4];
            const float sj = (j < 4) ? sA[j] : sB[j - 4];
            qo0[j] = (_Float16)(((float)q0[j] * cj - (float)q1[j] * sj) * QSCALE_LOG2E);
            qo1[j] = (_Float16)(((float)q1[j] * cj + (float)q0[j] * sj) * QSCALE_LOG2E);
            ko0[j] = (_Float16)((float)k0[j] * cj - (float)k1[j] * sj);
            ko1[j] = (_Float16)((float)k1[j] * cj + (float)k0[j] * sj);
        }
        const long o = ((long)h * SEQLEN + s0 + r) * HD;
        *(half8*)&Qh[o + d]      = qo0;
        *(half8*)&Qh[o + d + 40] = qo1;
        *(half8*)&Kh[o + d]      = ko0;
        *(half8*)&Kh[o + d + 40] = ko1;
    }
    __syncthreads();
    // transposed V out: 80 d-rows x 8 s-chunks
    for (int i = tid; i < 640; i += 256) {
        const int d = i >> 3, sc = (i & 7) * 8;
        half8 v;
#pragma unroll
        for (int j = 0; j < 8; j++) v[j] = Ts[(sc + j) * 88 + d];
        *(half8*)&Vt[((long)h * HD + d) * SEQLEN + s0 + sc] = v;
    }
}

// ---------------------------------------------------------------------------
// Flash attention (v6 schedule): 8 waves x 32 q-rows; 64-key tiles; split x4.
// Issue-early / wait-late staging; single K/V buffer, two barriers per tile.
__global__ __launch_bounds__(512, 4)
void attn_kernel(const _Float16* __restrict__ Qh, const _Float16* __restrict__ Kh,
                 const _Float16* __restrict__ Vt,
                 _Float16* __restrict__ Ohat0, _Float16* __restrict__ Ohat1,
                 float* __restrict__ Lpart) {
    const int s0 = blockIdx.x * 256;
    const int h  = blockIdx.y;
    const int z  = blockIdx.z;
    __shared__ __align__(16) _Float16 Ks[64 * KSTRIDE];        // 11.0 KB
    __shared__ __align__(16) _Float16 VF[5 * 64 * VFSTRIDE];   // 15.0 KB

    const int tid  = threadIdx.x;
    const int lane = tid & 63;
    const int wave = tid >> 6;
    const int l15  = lane & 15;
    const int quad = lane >> 4;

    const int zBeg = z * KVSPAN, zEnd = zBeg + KVSPAN;

    // Q fragments (persistent): two 16-row fragments, dense 80 each
    const _Float16* Qg0 = Qh + ((long)h * SEQLEN + s0 + wave * 32 + l15) * HD;
    const _Float16* Qg1 = Qg0 + 16 * (long)HD;
    const half8 qA0 = *(const half8*)&Qg0[quad * 8];
    const half8 qA1 = *(const half8*)&Qg0[32 + quad * 8];
    const half4 qA2 = *(const half4*)&Qg0[64 + quad * 4];
    const half8 qB0 = *(const half8*)&Qg1[quad * 8];
    const half8 qB1 = *(const half8*)&Qg1[32 + quad * 8];
    const half4 qB2 = *(const half4*)&Qg1[64 + quad * 4];

    // ---- hoisted staging assignment (all div/mod at init only) ----
    int offA, dsA, offB, dsB0, dsB1 = 0, offC = 0, dsC0 = 0, dsC1 = 0;
    {
        const int rA = tid / 10, cA = (tid - rA * 10) * 8;
        offA = rA * HD + cA;
        dsA  = rA * KSTRIDE + cA;
        if (tid < 128) {
            const int cB = tid + 512;
            const int rB = cB / 10, ccB = (cB - rB * 10) * 8;
            offB = rB * HD + ccB;
            dsB0 = rB * KSTRIDE + ccB;
        } else {
            const int v = tid - 128, d = v >> 3, c8 = (v & 7) * 8;
            offB = d * SEQLEN + c8;
            const int nt = d >> 4, ld = d & 15, ct = c8 >> 4, qb = (c8 & 15) >> 2;
            dsB0 = (nt * 64 + qb * 16 + ld) * VFSTRIDE + ct * 4;
            dsB1 = (nt * 64 + (qb + 1) * 16 + ld) * VFSTRIDE + ct * 4;
        }
        if (tid < 256) {
            const int v = tid + 384, d = v >> 3, c8 = (v & 7) * 8;
            offC = d * SEQLEN + c8;
            const int nt = d >> 4, ld = d & 15, ct = c8 >> 4, qb = (c8 & 15) >> 2;
            dsC0 = (nt * 64 + qb * 16 + ld) * VFSTRIDE + ct * 4;
            dsC1 = (nt * 64 + (qb + 1) * 16 + ld) * VFSTRIDE + ct * 4;
        }
    }
    const _Float16* KzBase = Kh + ((long)h * SEQLEN + zBeg) * HD;
    const _Float16* VzBase = Vt + (long)h * HD * SEQLEN + zBeg;

    // prologue: issue tile-0 loads (consumed by the first write)
    half8 sga, sgb, sgc = (half8)(_Float16)0.f;
    sga = *(const half8*)(KzBase + offA);
    if (tid < 128) sgb = *(const half8*)(KzBase + offB);
    else           sgb = *(const half8*)(VzBase + offB);
    if (tid < 256) sgc = *(const half8*)(VzBase + offC);

    f32x4 oaccA[5] = {}, oaccB[5] = {};
    float laA0 = 0.f, laA1 = 0.f, laB0 = 0.f, laB1 = 0.f;
    const half2v ones2 = {(_Float16)1.f, (_Float16)1.f};

    for (int t0 = zBeg; t0 < zEnd; t0 += 64) {
        __syncthreads();                   // readers of tile t-1 done
        *(half8*)&Ks[dsA] = sga;
        if (tid < 128) { *(half8*)&Ks[dsB0] = sgb; }
        else {
            *(half4*)&VF[dsB0] = lo4(sgb);
            *(half4*)&VF[dsB1] = hi4(sgb);
        }
        if (tid < 256) {
            *(half4*)&VF[dsC0] = lo4(sgc);
            *(half4*)&VF[dsC1] = hi4(sgc);
        }
        __syncthreads();                   // tile t published

        if (t0 + 64 < zEnd) {
            const _Float16* KzT = KzBase + (long)(t0 + 64 - zBeg) * HD;
            const _Float16* VzT = VzBase + (t0 + 64 - zBeg);
            sga = *(const half8*)(KzT + offA);
            if (tid < 128) sgb = *(const half8*)(KzT + offB);
            else           sgb = *(const half8*)(VzT + offB);
            if (tid < 256) sgc = *(const half8*)(VzT + offC);
        }

        // S^T: 4 col-tiles of 16 keys; each kf read feeds BOTH fragments.
        f32x4 saA[4] = {}, saB[4] = {};
        __builtin_amdgcn_s_setprio(1);
#pragma unroll
        for (int ct = 0; ct < 4; ct++) {
            const int kb = (ct * 16 + l15) * KSTRIDE;
            const half8 kf0 = *(const half8*)&Ks[kb + quad * 8];
            const half8 kf1 = *(const half8*)&Ks[kb + 32 + quad * 8];
            const half4 kf2 = *(const half4*)&Ks[kb + 64 + quad * 4];
            saA[ct] = mfma_16x16x32(kf0, qA0, saA[ct]);
            saB[ct] = mfma_16x16x32(kf0, qB0, saB[ct]);
            saA[ct] = mfma_16x16x32(kf1, qA1, saA[ct]);
            saB[ct] = mfma_16x16x32(kf1, qB1, saB[ct]);
            saA[ct] = mfma_16x16x16(kf2, qA2, saA[ct]);
            saB[ct] = mfma_16x16x16(kf2, qB2, saB[ct]);
        }
        __builtin_amdgcn_s_setprio(0);

        // P^T = exp2(S^T): cvt_pkrtz feeds the PV B-operand and v_dot2 l-accum
        half4 pbA[4], pbB[4];
#pragma unroll
        for (int ct = 0; ct < 4; ct++) {
            {
                const float e0 = EXP2F(saA[ct][0]);
                const float e1 = EXP2F(saA[ct][1]);
                const float e2 = EXP2F(saA[ct][2]);
                const float e3 = EXP2F(saA[ct][3]);
                const half2v p01 = __builtin_bit_cast(half2v, __builtin_amdgcn_cvt_pkrtz(e0, e1));
                const half2v p23 = __builtin_bit_cast(half2v, __builtin_amdgcn_cvt_pkrtz(e2, e3));
                laA0 = __builtin_amdgcn_fdot2(p01, ones2, laA0, false);
                laA1 = __builtin_amdgcn_fdot2(p23, ones2, laA1, false);
                pbA[ct] = __builtin_shufflevector(p01, p23, 0, 1, 2, 3);
            }
            {
                const float e0 = EXP2F(saB[ct][0]);
                const float e1 = EXP2F(saB[ct][1]);
                const float e2 = EXP2F(saB[ct][2]);
                const float e3 = EXP2F(saB[ct][3]);
                const half2v p01 = __builtin_bit_cast(half2v, __builtin_amdgcn_cvt_pkrtz(e0, e1));
                const half2v p23 = __builtin_bit_cast(half2v, __builtin_amdgcn_cvt_pkrtz(e2, e3));
                laB0 = __builtin_amdgcn_fdot2(p01, ones2, laB0, false);
                laB1 = __builtin_amdgcn_fdot2(p23, ones2, laB1, false);
                pbB[ct] = __builtin_shufflevector(p01, p23, 0, 1, 2, 3);
            }
        }

        // O^T += V^T * P^T : each va/vb read feeds BOTH fragments
        __builtin_amdgcn_s_setprio(1);
#pragma unroll
        for (int nt = 0; nt < 5; nt++) {
            const half8 va = *(const half8*)&VF[(nt * 64 + lane) * VFSTRIDE];
            const half8 vb = *(const half8*)&VF[(nt * 64 + lane) * VFSTRIDE + 8];
            oaccA[nt] = mfma_16x16x16(lo4(va), pbA[0], oaccA[nt]);
            oaccB[nt] = mfma_16x16x16(lo4(va), pbB[0], oaccB[nt]);
            oaccA[nt] = mfma_16x16x16(hi4(va), pbA[1], oaccA[nt]);
            oaccB[nt] = mfma_16x16x16(hi4(va), pbB[1], oaccB[nt]);
            oaccA[nt] = mfma_16x16x16(lo4(vb), pbA[2], oaccA[nt]);
            oaccB[nt] = mfma_16x16x16(lo4(vb), pbB[2], oaccB[nt]);
            oaccA[nt] = mfma_16x16x16(hi4(vb), pbA[3], oaccA[nt]);
            oaccB[nt] = mfma_16x16x16(hi4(vb), pbB[3], oaccB[nt]);
        }
        __builtin_amdgcn_s_setprio(0);
    }

    // l: sum the 4 quads holding each query's key-chunks
    float lA = laA0 + laA1, lB = laB0 + laB1;
    lA += __shfl_xor(lA, 16); lA += __shfl_xor(lA, 32);
    lB += __shfl_xor(lB, 16); lB += __shfl_xor(lB, 32);
    const float invA = 1.0f / lA, invB = 1.0f / lB;

    // partials: z 0,1 -> Ohat0 region, z 2,3 -> Ohat1 region
    _Float16* Oz = (z < 2) ? Ohat0 : Ohat1;
    const long obase = ((long)(z & 1) * NHEADS + h) * SEQLEN;
    const long lbase = ((long)z * NHEADS + h) * SEQLEN;
    const long rowA = s0 + wave * 32 + l15;
    const long rowB = rowA + 16;
#pragma unroll
    for (int nt = 0; nt < 5; nt++) {
        half4 oA, oB;
#pragma unroll
        for (int r = 0; r < 4; r++) {
            oA[r] = (_Float16)(oaccA[nt][r] * invA);
            oB[r] = (_Float16)(oaccB[nt][r] * invB);
        }
        *(half4*)&Oz[(obase + rowA) * HD + nt * 16 + quad * 4] = oA;
        *(half4*)&Oz[(obase + rowB) * HD + nt * 16 + quad * 4] = oB;
    }
    if (quad == 0) {
        Lpart[lbase + rowA] = lA;
        Lpart[lbase + rowB] = lB;
    }
}

// ---------------------------------------------------------------------------
// out = sum_z Ohat_z * l_z / sum_z l_z  -> attnb f16 [s][h*80+d]
// half8-wide (16B/lane); 8-chunks never straddle heads (8 | 80).
__global__ __launch_bounds__(256)
void attn_combine(const _Float16* __restrict__ Ohat0,
                  const _Float16* __restrict__ Ohat1,
                  const float* __restrict__ Lp,
                  _Float16* __restrict__ attnb) {
    const int i = blockIdx.x * 256 + threadIdx.x;
    if (i >= SEQLEN * DIMM / 8) return;
    const int flat = i * 8;
    const int s = flat / DIMM;
    const int rem = flat - s * DIMM;
    const int h = rem / HD;
    const int d = rem - h * HD;
    float l[NSPLIT], lsum = 0.f;
#pragma unroll
    for (int zi = 0; zi < NSPLIT; zi++) {
        l[zi] = Lp[((long)zi * NHEADS + h) * SEQLEN + s];
        lsum += l[zi];
    }
    const float invl = 1.0f / lsum;
    float acc[8] = {};
#pragma unroll
    for (int zi = 0; zi < NSPLIT; zi++) {
        const _Float16* Oz = (zi < 2) ? Ohat0 : Ohat1;
        const long obase = ((long)(zi & 1) * NHEADS + h) * SEQLEN;
        const half8 o = *(const half8*)&Oz[(obase + s) * HD + d];
        const float w = l[zi] * invl;
#pragma unroll
        for (int j = 0; j < 8; j++) acc[j] += (float)o[j] * w;
    }
    half8 o;
#pragma unroll
    for (int j = 0; j < 8; j++) o[j] = (_Float16)acc[j];
    *(half8*)&attnb[(long)s * DIMM + rem] = o;
}

// ---------------------------------------------------------------------------
extern "C" void kernel_launch(void* const* d_in, const int* in_sizes, int n_in,
                              void* d_out, int out_size, void* d_ws, size_t ws_size,
                              hipStream_t stream) {
    const float* hs     = (const float*)d_in[0];
    // d_in[1] = cu_seqlens [0, 2048] — reference does no masking; unused.
    const float* cosb   = (const float*)d_in[2];
    const float* sinb   = (const float*)d_in[3];
    const float* w_qkv  = (const float*)d_in[4];
    const float* b_qkv  = (const float*)d_in[5];
    const float* w_proj = (const float*)d_in[6];
    const float* b_proj = (const float*)d_in[7];
    float* out = (float*)d_out;

    _Float16* hsb    = (_Float16*)d_ws;                       // 2048*1280
    _Float16* wqkvb  = hsb    + (long)SEQLEN * DIMM;          // 3840*1280
    _Float16* wprojb = wqkvb  + (long)QKV_N * DIMM;           // 1280*1280
    _Float16* qkv    = wprojb + (long)DIMM * DIMM;            // 2048*3840
    _Float16* Qh     = qkv    + (long)SEQLEN * QKV_N;         // 16*2048*80
    _Float16* Kh     = Qh     + (long)NHEADS * SEQLEN * HD;
    _Float16* Vtb    = Kh     + (long)NHEADS * SEQLEN * HD;   // 16*80*2048
    _Float16* attnb  = Vtb    + (long)NHEADS * HD * SEQLEN;   // 2048*1280

    // attention partials alias DEAD regions during attention:
    //   Ohat0 (z=0,1): hsb+wqkvb region (15.07 MB) — dead after QKV GEMM.
    //   Ohat1 (z=2,3): qkv region (15.73 MB) — dead after rope_repack_t.
    _Float16* Ohat0  = (_Float16*)d_ws;
    float*    LpartB = (float*)(Ohat0 + (long)2 * NHEADS * SEQLEN * HD);
    _Float16* Ohat1  = qkv;

    {
        const int ntot = (SEQLEN * DIMM + QKV_N * DIMM + DIMM * DIMM) / 4;
        cast_all<<<(ntot + 255) / 256, 256, 0, stream>>>(
            hs, w_qkv, w_proj, hsb, wqkvb, wprojb);
    }

    gemm_bt128<true><<<dim3(SEQLEN / 128, QKV_N / 128), 512, 0, stream>>>(
        hsb, wqkvb, b_qkv, qkv, SEQLEN, QKV_N, DIMM);

    rope_repack_t<<<dim3(SEQLEN / 64, NHEADS), 256, 0, stream>>>(
        qkv, cosb, sinb, Qh, Kh, Vtb);

    attn_kernel<<<dim3(SEQLEN / 256, NHEADS, NSPLIT), 512, 0, stream>>>(
        Qh, Kh, Vtb, Ohat0, Ohat1, LpartB);

    attn_combine<<<(SEQLEN * DIMM / 8 + 255) / 256, 256, 0, stream>>>(
        Ohat0, Ohat1, LpartB, attnb);

    gemm_bt64<false><<<dim3(SEQLEN / 64, DIMM / 128), 256, 0, stream>>>(
        attnb, wprojb, b_proj, out, SEQLEN, DIMM, DIMM);
}

// Round 9
// 186.784 us; speedup vs baseline: 1.0107x; 1.0107x over previous
//
#include <hip/hip_runtime.h>

// ---------------------------------------------------------------------------
// SimpleVisionAttention on MI355X (gfx950)
// S=2048, DIM=1280 (16 heads x 80), fp32 in/out, f16 MFMA internally.
//
// Pipeline:
//   K1  fused cast fp32 -> f16   (hs, w_qkv, w_proj)
//   K2  QKV GEMM  128x128 tiles, 8 waves, BK=64 dual-panel (v4 form)
//   K3  fused RoPE + repack Qh/Kh [h][s][80] (dense) + V transpose -> Vt[h][d][s]
//   K4  flash attention v8: KVBLK=128 staged tiles (barrier pairs per block
//       8 -> 4), computed as TWO sequential 64-key halves so transient
//       VGPRs (sa/pb) stay at v4 levels; staging regs 12->20 held across
//       one barrier only. LDS 52 KB -> still 2 blocks/CU = 16 waves/CU.
//       (v5 dbuf / v6 issue-early / v7 GEMM-dbuf all measured neutral:
//       TLP at 16 waves/CU hides what lockstep reordering re-arranges;
//       only phase-count / work-density changes have paid.)
//   K4b combine 4 partials, half8-wide
//   K5  proj GEMM 64x128 tiles (v4 form)
// ---------------------------------------------------------------------------

#define SEQLEN   2048
#define DIMM     1280
#define NHEADS   16
#define HD       80
#define QKV_N    3840
#define NSPLIT   4
#define KVSPAN   (SEQLEN / NSPLIT)
#define KVBLK    128
// SCALE * log2(e) folded into Q at rope time; softmax done in base-2.
#define QSCALE_LOG2E 0.16130083587064776f   // 80^-0.5 * 1.4426950408889634

#define KSTRIDE  88   // K-tile row stride (44 dw): 8-bank spread, 2-way = free
#define VFSTRIDE 24   // VF row stride (12 dw): balanced lane->bank spread
#define VHALF    (5 * 64 * VFSTRIDE)   // one 64-key V sub-block (halves)

// device base-2 exp: v_exp_f32 (NOT __exp2f — collides with glibc math.h)
#define EXP2F(x) __builtin_amdgcn_exp2f(x)

// async global->LDS, 16B per lane; LDS dest must be waveBase + lane*16
#define GLD16(gptr, lptr)                                                      \
    __builtin_amdgcn_global_load_lds(                                          \
        (const __attribute__((address_space(1))) void*)(gptr),                 \
        (__attribute__((address_space(3))) void*)(lptr), 16, 0, 0)

typedef float f32x4 __attribute__((ext_vector_type(4)));
typedef _Float16 half8 __attribute__((ext_vector_type(8)));
typedef _Float16 half4 __attribute__((ext_vector_type(4)));
typedef _Float16 half2v __attribute__((ext_vector_type(2)));

static __device__ __forceinline__ f32x4 mfma_16x16x32(half8 a, half8 b, f32x4 c) {
    return __builtin_amdgcn_mfma_f32_16x16x32_f16(a, b, c, 0, 0, 0);
}
// NOTE: legacy K=16 shape is spelled WITHOUT the underscore: ...16x16x16f16
static __device__ __forceinline__ f32x4 mfma_16x16x16(half4 a, half4 b, f32x4 c) {
    return __builtin_amdgcn_mfma_f32_16x16x16f16(a, b, c, 0, 0, 0);
}
static __device__ __forceinline__ half4 lo4(half8 v) {
    return __builtin_shufflevector(v, v, 0, 1, 2, 3);
}
static __device__ __forceinline__ half4 hi4(half8 v) {
    return __builtin_shufflevector(v, v, 4, 5, 6, 7);
}

// ---------------------------------------------------------------------------
// One fused cast kernel for the three fp32->f16 conversions.
__global__ __launch_bounds__(256)
void cast_all(const float* __restrict__ hs, const float* __restrict__ wq,
              const float* __restrict__ wp, _Float16* __restrict__ dhs,
              _Float16* __restrict__ dwq, _Float16* __restrict__ dwp) {
    const int n1 = SEQLEN * DIMM / 4, n2 = QKV_N * DIMM / 4, n3 = DIMM * DIMM / 4;
    int i = blockIdx.x * 256 + threadIdx.x;
    const float4* src; half4* dst; int j;
    if (i < n1)           { src = (const float4*)hs; dst = (half4*)dhs; j = i; }
    else if (i < n1 + n2) { src = (const float4*)wq; dst = (half4*)dwq; j = i - n1; }
    else if (i < n1 + n2 + n3) { src = (const float4*)wp; dst = (half4*)dwp; j = i - n1 - n2; }
    else return;
    const float4 v = src[j];
    half4 h;
    h.x = (_Float16)v.x; h.y = (_Float16)v.y;
    h.z = (_Float16)v.z; h.w = (_Float16)v.w;
    dst[j] = h;
}

// ---------------------------------------------------------------------------
// 128x128 block tile, 8 waves 4x2 (each 32x64, 2x4 mfma tiles), BK=64 as two
// BK=32 panels (v4 form; dbuf variant measured neutral). 32 KB LDS.
template<bool OUT_F16>
__global__ __launch_bounds__(512, 4)
void gemm_bt128(const _Float16* __restrict__ A, const _Float16* __restrict__ B,
                const float* __restrict__ bias, void* __restrict__ Cout,
                int M, int N, int K) {
    __shared__ __align__(16) _Float16 As[2][128 * 32];   // 16 KB
    __shared__ __align__(16) _Float16 Bs[2][128 * 32];   // 16 KB
    const int tid  = threadIdx.x;
    const int lane = tid & 63;
    const int wave = tid >> 6;
    const int l15  = lane & 15;
    const int quad = lane >> 4;
    const int wm   = wave & 3;           // 4 row-waves of 32
    const int wn   = wave >> 2;          // 2 col-waves of 64
    const long bm = blockIdx.x, bn = blockIdx.y;

    const _Float16* Ag = A + bm * 128 * (long)K;
    const _Float16* Bg = B + bn * 128 * (long)K;

    const int srow = lane >> 2;            // 0..15 within wave's 16-row strip
    const int scol = (lane & 3) * 8;       // halves
    f32x4 acc[2][4] = {};

    for (int k0 = 0; k0 < K; k0 += 64) {
        __syncthreads();
#pragma unroll
        for (int p = 0; p < 2; p++) {
            const int kp = k0 + p * 32;
            const long r = 16 * wave + srow;        // 0..127
            GLD16(Ag + r * K + kp + scol, &As[p][512 * wave + lane * 8]);
            GLD16(Bg + r * K + kp + scol, &Bs[p][512 * wave + lane * 8]);
        }
        __syncthreads();
#pragma unroll
        for (int p = 0; p < 2; p++) {
            half8 af[2], bf[4];
#pragma unroll
            for (int t = 0; t < 2; t++)
                af[t] = *(const half8*)&As[p][(wm * 32 + t * 16 + l15) * 32 + quad * 8];
#pragma unroll
            for (int t = 0; t < 4; t++)
                bf[t] = *(const half8*)&Bs[p][(wn * 64 + t * 16 + l15) * 32 + quad * 8];
#pragma unroll
            for (int mt = 0; mt < 2; mt++)
#pragma unroll
                for (int nt = 0; nt < 4; nt++)
                    acc[mt][nt] = mfma_16x16x32(af[mt], bf[nt], acc[mt][nt]);
        }
    }

    float bv[4];
#pragma unroll
    for (int nt = 0; nt < 4; nt++)
        bv[nt] = bias[bn * 128 + wn * 64 + nt * 16 + l15];

#pragma unroll
    for (int mt = 0; mt < 2; mt++) {
#pragma unroll
        for (int r = 0; r < 4; r++) {
            const long row = bm * 128 + wm * 32 + mt * 16 + quad * 4 + r;
#pragma unroll
            for (int nt = 0; nt < 4; nt++) {
                const long col = bn * 128 + wn * 64 + nt * 16 + l15;
                const float v = acc[mt][nt][r] + bv[nt];
                if (OUT_F16) ((_Float16*)Cout)[row * (long)N + col] = (_Float16)v;
                else         ((float*)Cout)[row * (long)N + col] = v;
            }
        }
    }
}

// ---------------------------------------------------------------------------
// 64x128 tile, 4 waves (proj GEMM; v4 form).
template<bool OUT_F16>
__global__ __launch_bounds__(256, 2)
void gemm_bt64(const _Float16* __restrict__ A, const _Float16* __restrict__ B,
               const float* __restrict__ bias, void* __restrict__ Cout,
               int M, int N, int K) {
    __shared__ __align__(16) _Float16 As[2][64 * 32];    // 8 KB
    __shared__ __align__(16) _Float16 Bs[2][128 * 32];   // 16 KB
    const int tid  = threadIdx.x;
    const int lane = tid & 63;
    const int wave = tid >> 6;
    const int l15  = lane & 15;
    const int quad = lane >> 4;
    const int wm   = wave & 1;
    const int wn   = wave >> 1;
    const long bm = blockIdx.x, bn = blockIdx.y;

    const _Float16* Ag = A + bm * 64 * (long)K;
    const _Float16* Bg = B + bn * 128 * (long)K;

    const int srow = lane >> 2;            // 0..15 within chunk
    const int scol = (lane & 3) * 8;       // halves
    f32x4 acc[2][4] = {};

    for (int k0 = 0; k0 < K; k0 += 64) {
        __syncthreads();
#pragma unroll
        for (int p = 0; p < 2; p++) {
            const int kp = k0 + p * 32;
            const long arow = 16 * wave + srow;
            GLD16(Ag + arow * K + kp + scol, &As[p][512 * wave + lane * 8]);
#pragma unroll
            for (int cc = 0; cc < 2; cc++) {
                const int c = wave + cc * 4;
                const long brow = 16 * c + srow;
                GLD16(Bg + brow * K + kp + scol, &Bs[p][512 * c + lane * 8]);
            }
        }
        __syncthreads();
#pragma unroll
        for (int p = 0; p < 2; p++) {
            half8 af[2], bf[4];
#pragma unroll
            for (int t = 0; t < 2; t++)
                af[t] = *(const half8*)&As[p][(wm * 32 + t * 16 + l15) * 32 + quad * 8];
#pragma unroll
            for (int t = 0; t < 4; t++)
                bf[t] = *(const half8*)&Bs[p][(wn * 64 + t * 16 + l15) * 32 + quad * 8];
#pragma unroll
            for (int mt = 0; mt < 2; mt++)
#pragma unroll
                for (int nt = 0; nt < 4; nt++)
                    acc[mt][nt] = mfma_16x16x32(af[mt], bf[nt], acc[mt][nt]);
        }
    }

    float bv[4];
#pragma unroll
    for (int nt = 0; nt < 4; nt++)
        bv[nt] = bias[bn * 128 + wn * 64 + nt * 16 + l15];

#pragma unroll
    for (int mt = 0; mt < 2; mt++) {
#pragma unroll
        for (int r = 0; r < 4; r++) {
            const long row = bm * 64 + wm * 32 + mt * 16 + quad * 4 + r;
#pragma unroll
            for (int nt = 0; nt < 4; nt++) {
                const long col = bn * 128 + wn * 64 + nt * 16 + l15;
                const float v = acc[mt][nt][r] + bv[nt];
                if (OUT_F16) ((_Float16*)Cout)[row * (long)N + col] = (_Float16)v;
                else         ((float*)Cout)[row * (long)N + col] = v;
            }
        }
    }
}

// ---------------------------------------------------------------------------
// Fused: RoPE on q,k -> Qh/Kh [h][s][80] dense (Q pre-scaled by SCALE*log2e)
// + V transposed via LDS -> Vt[h][d][s]. Block = (64 seqs, 1 head).
__global__ __launch_bounds__(256)
void rope_repack_t(const _Float16* __restrict__ qkv,
                   const float* __restrict__ cosb,
                   const float* __restrict__ sinb,
                   _Float16* __restrict__ Qh,
                   _Float16* __restrict__ Kh,
                   _Float16* __restrict__ Vt) {
    const int s0 = blockIdx.x * 64;
    const int h  = blockIdx.y;
    __shared__ __align__(16) _Float16 Ts[64 * 88];
    const int tid = threadIdx.x;

    // stage V rows into LDS (transposed write later)
    for (int i = tid; i < 640; i += 256) {          // 64 rows x 10 chunks
        const int r = i / 10, c = (i - r * 10) * 8;
        *(half8*)&Ts[r * 88 + c] =
            *(const half8*)&qkv[(long)(s0 + r) * QKV_N + 2 * DIMM + h * HD + c];
    }

    // q,k rope: 64 rows x 5 chunks of 8 (d in [0,40))
    for (int i = tid; i < 320; i += 256) {
        const int r = i / 5, d = (i - r * 5) * 8;
        const _Float16* row = qkv + (long)(s0 + r) * QKV_N + h * HD;
        const half8 q0 = *(const half8*)&row[d];
        const half8 q1 = *(const half8*)&row[d + 40];
        const half8 k0 = *(const half8*)&row[DIMM + d];
        const half8 k1 = *(const half8*)&row[DIMM + d + 40];
        const float4 cA = *(const float4*)&cosb[(s0 + r) * HD + d];
        const float4 cB = *(const float4*)&cosb[(s0 + r) * HD + d + 4];
        const float4 sA = *(const float4*)&sinb[(s0 + r) * HD + d];
        const float4 sB = *(const float4*)&sinb[(s0 + r) * HD + d + 4];
        half8 qo0, qo1, ko0, ko1;
#pragma unroll
        for (int j = 0; j < 8; j++) {
            const float cj = (j < 4) ? cA[j] : cB[j - 4];
            const float sj = (j < 4) ? sA[j] : sB[j - 4];
            qo0[j] = (_Float16)(((float)q0[j] * cj - (float)q1[j] * sj) * QSCALE_LOG2E);
            qo1[j] = (_Float16)(((float)q1[j] * cj + (float)q0[j] * sj) * QSCALE_LOG2E);
            ko0[j] = (_Float16)((float)k0[j] * cj - (float)k1[j] * sj);
            ko1[j] = (_Float16)((float)k1[j] * cj + (float)k0[j] * sj);
        }
        const long o = ((long)h * SEQLEN + s0 + r) * HD;
        *(half8*)&Qh[o + d]      = qo0;
        *(half8*)&Qh[o + d + 40] = qo1;
        *(half8*)&Kh[o + d]      = ko0;
        *(half8*)&Kh[o + d + 40] = ko1;
    }
    __syncthreads();
    // transposed V out: 80 d-rows x 8 s-chunks
    for (int i = tid; i < 640; i += 256) {
        const int d = i >> 3, sc = (i & 7) * 8;
        half8 v;
#pragma unroll
        for (int j = 0; j < 8; j++) v[j] = Ts[(sc + j) * 88 + d];
        *(half8*)&Vt[((long)h * HD + d) * SEQLEN + s0 + sc] = v;
    }
}

// ---------------------------------------------------------------------------
// Flash attention v8: 8 waves x 32 q-rows; KVBLK=128 staged tiles computed
// as two sequential 64-key halves; KV-split x4 (grid 512 blocks, 2/CU).
// Per tile: { loads(5x half8); bar1; write->LDS; bar2; compute half0;
// compute half1 }. Barrier pairs per block: 4 (was 8 at KVBLK=64);
// transient VGPRs (sa[4]/pb[4]) unchanged vs v4; staging regs 20, held
// across one barrier only. LDS 52 KB -> 2 blocks/CU.
__global__ __launch_bounds__(512, 4)
void attn_kernel(const _Float16* __restrict__ Qh, const _Float16* __restrict__ Kh,
                 const _Float16* __restrict__ Vt,
                 _Float16* __restrict__ Ohat0, _Float16* __restrict__ Ohat1,
                 float* __restrict__ Lpart) {
    const int s0 = blockIdx.x * 256;
    const int h  = blockIdx.y;
    const int z  = blockIdx.z;
    __shared__ __align__(16) _Float16 Ks[KVBLK * KSTRIDE];   // 22.0 KB
    __shared__ __align__(16) _Float16 VF[2 * VHALF];         // 30.0 KB

    const int tid  = threadIdx.x;
    const int lane = tid & 63;
    const int wave = tid >> 6;
    const int l15  = lane & 15;
    const int quad = lane >> 4;

    const int zBeg = z * KVSPAN, zEnd = zBeg + KVSPAN;

    // Q fragments (persistent): two 16-row fragments, dense 80 each
    const _Float16* Qg0 = Qh + ((long)h * SEQLEN + s0 + wave * 32 + l15) * HD;
    const _Float16* Qg1 = Qg0 + 16 * (long)HD;
    const half8 qA0 = *(const half8*)&Qg0[quad * 8];
    const half8 qA1 = *(const half8*)&Qg0[32 + quad * 8];
    const half4 qA2 = *(const half4*)&Qg0[64 + quad * 4];
    const half8 qB0 = *(const half8*)&Qg1[quad * 8];
    const half8 qB1 = *(const half8*)&Qg1[32 + quad * 8];
    const half4 qB2 = *(const half4*)&Qg1[64 + quad * 4];

    // ---- hoisted staging assignment (all div/mod at init only) ----
    // K: 128 rows x 10 chunks = 1280; V: 80 d-rows x 16 s-chunks = 1280.
    // Total 2560 = 512 x 5 slots:
    //  A (all):      K [0,512)        B (all):     K [512,1024)
    //  C (tid<256):  K [1024,1280)  | (tid>=256):  V [0,256)    (d 0..15)
    //  D (all):      V [256,768)   (d 16..47)
    //  E (all):      V [768,1280)  (d 48..79)
    // V chunk vi -> d = vi>>4, c8 = (vi&15)*8; half = c8>>6 selects VF block.
    int offA, dsA, offB, dsB, offC, dsC0, dsC1 = 0;
    int offD, dsD0, dsD1, offE, dsE0, dsE1;
    {
        const int rA = tid / 10, cA = (tid - rA * 10) * 8;
        offA = rA * HD + cA;  dsA = rA * KSTRIDE + cA;
        const int iB = tid + 512;
        const int rB = iB / 10, cB = (iB - rB * 10) * 8;
        offB = rB * HD + cB;  dsB = rB * KSTRIDE + cB;
        if (tid < 256) {
            const int iC = tid + 1024;
            const int rC = iC / 10, cC = (iC - rC * 10) * 8;
            offC = rC * HD + cC;  dsC0 = rC * KSTRIDE + cC;
        } else {
            const int vi = tid - 256, d = vi >> 4, c8 = (vi & 15) * 8;
            offC = d * SEQLEN + c8;
            const int hf = c8 >> 6, c8l = c8 & 63;
            const int nt = d >> 4, ld = d & 15, ct = c8l >> 4, qb = (c8l & 15) >> 2;
            dsC0 = hf * VHALF + (nt * 64 + qb * 16 + ld) * VFSTRIDE + ct * 4;
            dsC1 = hf * VHALF + (nt * 64 + (qb + 1) * 16 + ld) * VFSTRIDE + ct * 4;
        }
        {
            const int vi = tid + 256, d = vi >> 4, c8 = (vi & 15) * 8;
            offD = d * SEQLEN + c8;
            const int hf = c8 >> 6, c8l = c8 & 63;
            const int nt = d >> 4, ld = d & 15, ct = c8l >> 4, qb = (c8l & 15) >> 2;
            dsD0 = hf * VHALF + (nt * 64 + qb * 16 + ld) * VFSTRIDE + ct * 4;
            dsD1 = hf * VHALF + (nt * 64 + (qb + 1) * 16 + ld) * VFSTRIDE + ct * 4;
        }
        {
            const int vi = tid + 768, d = vi >> 4, c8 = (vi & 15) * 8;
            offE = d * SEQLEN + c8;
            const int hf = c8 >> 6, c8l = c8 & 63;
            const int nt = d >> 4, ld = d & 15, ct = c8l >> 4, qb = (c8l & 15) >> 2;
            dsE0 = hf * VHALF + (nt * 64 + qb * 16 + ld) * VFSTRIDE + ct * 4;
            dsE1 = hf * VHALF + (nt * 64 + (qb + 1) * 16 + ld) * VFSTRIDE + ct * 4;
        }
    }
    const _Float16* KzBase = Kh + ((long)h * SEQLEN + zBeg) * HD;
    const _Float16* VzBase = Vt + (long)h * HD * SEQLEN + zBeg;

    f32x4 oaccA[5] = {}, oaccB[5] = {};
    float laA0 = 0.f, laA1 = 0.f, laB0 = 0.f, laB1 = 0.f;
    const half2v ones2 = {(_Float16)1.f, (_Float16)1.f};

    for (int t0 = zBeg; t0 < zEnd; t0 += KVBLK) {
        // loads for this tile (issued just before the barrier; short live range)
        const _Float16* KzT = KzBase + (long)(t0 - zBeg) * HD;
        const _Float16* VzT = VzBase + (t0 - zBeg);
        const half8 sga = *(const half8*)(KzT + offA);
        const half8 sgb = *(const half8*)(KzT + offB);
        half8 sgc;
        if (tid < 256) sgc = *(const half8*)(KzT + offC);
        else           sgc = *(const half8*)(VzT + offC);
        const half8 sgd = *(const half8*)(VzT + offD);
        const half8 sge = *(const half8*)(VzT + offE);

        __syncthreads();                       // readers of previous tile done
        *(half8*)&Ks[dsA] = sga;
        *(half8*)&Ks[dsB] = sgb;
        if (tid < 256) { *(half8*)&Ks[dsC0] = sgc; }
        else {
            *(half4*)&VF[dsC0] = lo4(sgc);
            *(half4*)&VF[dsC1] = hi4(sgc);
        }
        *(half4*)&VF[dsD0] = lo4(sgd);
        *(half4*)&VF[dsD1] = hi4(sgd);
        *(half4*)&VF[dsE0] = lo4(sge);
        *(half4*)&VF[dsE1] = hi4(sge);
        __syncthreads();                       // tile published

#pragma unroll
        for (int hf = 0; hf < 2; hf++) {
            // S^T: 4 col-tiles of 16 keys; each kf read feeds BOTH fragments.
            f32x4 saA[4] = {}, saB[4] = {};
            __builtin_amdgcn_s_setprio(1);
#pragma unroll
            for (int ct = 0; ct < 4; ct++) {
                const int kb = (hf * 64 + ct * 16 + l15) * KSTRIDE;
                const half8 kf0 = *(const half8*)&Ks[kb + quad * 8];
                const half8 kf1 = *(const half8*)&Ks[kb + 32 + quad * 8];
                const half4 kf2 = *(const half4*)&Ks[kb + 64 + quad * 4];
                saA[ct] = mfma_16x16x32(kf0, qA0, saA[ct]);
                saB[ct] = mfma_16x16x32(kf0, qB0, saB[ct]);
                saA[ct] = mfma_16x16x32(kf1, qA1, saA[ct]);
                saB[ct] = mfma_16x16x32(kf1, qB1, saB[ct]);
                saA[ct] = mfma_16x16x16(kf2, qA2, saA[ct]);
                saB[ct] = mfma_16x16x16(kf2, qB2, saB[ct]);
            }
            __builtin_amdgcn_s_setprio(0);

            // P^T = exp2(S^T): cvt_pkrtz feeds PV B-operand and v_dot2 l-accum
            half4 pbA[4], pbB[4];
#pragma unroll
            for (int ct = 0; ct < 4; ct++) {
                {
                    const float e0 = EXP2F(saA[ct][0]);
                    const float e1 = EXP2F(saA[ct][1]);
                    const float e2 = EXP2F(saA[ct][2]);
                    const float e3 = EXP2F(saA[ct][3]);
                    const half2v p01 = __builtin_bit_cast(half2v, __builtin_amdgcn_cvt_pkrtz(e0, e1));
                    const half2v p23 = __builtin_bit_cast(half2v, __builtin_amdgcn_cvt_pkrtz(e2, e3));
                    laA0 = __builtin_amdgcn_fdot2(p01, ones2, laA0, false);
                    laA1 = __builtin_amdgcn_fdot2(p23, ones2, laA1, false);
                    pbA[ct] = __builtin_shufflevector(p01, p23, 0, 1, 2, 3);
                }
                {
                    const float e0 = EXP2F(saB[ct][0]);
                    const float e1 = EXP2F(saB[ct][1]);
                    const float e2 = EXP2F(saB[ct][2]);
                    const float e3 = EXP2F(saB[ct][3]);
                    const half2v p01 = __builtin_bit_cast(half2v, __builtin_amdgcn_cvt_pkrtz(e0, e1));
                    const half2v p23 = __builtin_bit_cast(half2v, __builtin_amdgcn_cvt_pkrtz(e2, e3));
                    laB0 = __builtin_amdgcn_fdot2(p01, ones2, laB0, false);
                    laB1 = __builtin_amdgcn_fdot2(p23, ones2, laB1, false);
                    pbB[ct] = __builtin_shufflevector(p01, p23, 0, 1, 2, 3);
                }
            }

            // O^T += V^T * P^T : each va/vb read feeds BOTH fragments
            __builtin_amdgcn_s_setprio(1);
#pragma unroll
            for (int nt = 0; nt < 5; nt++) {
                const int vb0 = hf * VHALF + (nt * 64 + lane) * VFSTRIDE;
                const half8 va = *(const half8*)&VF[vb0];
                const half8 vb = *(const half8*)&VF[vb0 + 8];
                oaccA[nt] = mfma_16x16x16(lo4(va), pbA[0], oaccA[nt]);
                oaccB[nt] = mfma_16x16x16(lo4(va), pbB[0], oaccB[nt]);
                oaccA[nt] = mfma_16x16x16(hi4(va), pbA[1], oaccA[nt]);
                oaccB[nt] = mfma_16x16x16(hi4(va), pbB[1], oaccB[nt]);
                oaccA[nt] = mfma_16x16x16(lo4(vb), pbA[2], oaccA[nt]);
                oaccB[nt] = mfma_16x16x16(lo4(vb), pbB[2], oaccB[nt]);
                oaccA[nt] = mfma_16x16x16(hi4(vb), pbA[3], oaccA[nt]);
                oaccB[nt] = mfma_16x16x16(hi4(vb), pbB[3], oaccB[nt]);
            }
            __builtin_amdgcn_s_setprio(0);
        }
    }

    // l: sum the 4 quads holding each query's key-chunks
    float lA = laA0 + laA1, lB = laB0 + laB1;
    lA += __shfl_xor(lA, 16); lA += __shfl_xor(lA, 32);
    lB += __shfl_xor(lB, 16); lB += __shfl_xor(lB, 32);
    const float invA = 1.0f / lA, invB = 1.0f / lB;

    // partials: z 0,1 -> Ohat0 region, z 2,3 -> Ohat1 region
    _Float16* Oz = (z < 2) ? Ohat0 : Ohat1;
    const long obase = ((long)(z & 1) * NHEADS + h) * SEQLEN;
    const long lbase = ((long)z * NHEADS + h) * SEQLEN;
    const long rowA = s0 + wave * 32 + l15;
    const long rowB = rowA + 16;
#pragma unroll
    for (int nt = 0; nt < 5; nt++) {
        half4 oA, oB;
#pragma unroll
        for (int r = 0; r < 4; r++) {
            oA[r] = (_Float16)(oaccA[nt][r] * invA);
            oB[r] = (_Float16)(oaccB[nt][r] * invB);
        }
        *(half4*)&Oz[(obase + rowA) * HD + nt * 16 + quad * 4] = oA;
        *(half4*)&Oz[(obase + rowB) * HD + nt * 16 + quad * 4] = oB;
    }
    if (quad == 0) {
        Lpart[lbase + rowA] = lA;
        Lpart[lbase + rowB] = lB;
    }
}

// ---------------------------------------------------------------------------
// out = sum_z Ohat_z * l_z / sum_z l_z  -> attnb f16 [s][h*80+d]
// half8-wide (16B/lane); 8-chunks never straddle heads (8 | 80).
__global__ __launch_bounds__(256)
void attn_combine(const _Float16* __restrict__ Ohat0,
                  const _Float16* __restrict__ Ohat1,
                  const float* __restrict__ Lp,
                  _Float16* __restrict__ attnb) {
    const int i = blockIdx.x * 256 + threadIdx.x;
    if (i >= SEQLEN * DIMM / 8) return;
    const int flat = i * 8;
    const int s = flat / DIMM;
    const int rem = flat - s * DIMM;
    const int h = rem / HD;
    const int d = rem - h * HD;
    float l[NSPLIT], lsum = 0.f;
#pragma unroll
    for (int zi = 0; zi < NSPLIT; zi++) {
        l[zi] = Lp[((long)zi * NHEADS + h) * SEQLEN + s];
        lsum += l[zi];
    }
    const float invl = 1.0f / lsum;
    float acc[8] = {};
#pragma unroll
    for (int zi = 0; zi < NSPLIT; zi++) {
        const _Float16* Oz = (zi < 2) ? Ohat0 : Ohat1;
        const long obase = ((long)(zi & 1) * NHEADS + h) * SEQLEN;
        const half8 o = *(const half8*)&Oz[(obase + s) * HD + d];
        const float w = l[zi] * invl;
#pragma unroll
        for (int j = 0; j < 8; j++) acc[j] += (float)o[j] * w;
    }
    half8 o;
#pragma unroll
    for (int j = 0; j < 8; j++) o[j] = (_Float16)acc[j];
    *(half8*)&attnb[(long)s * DIMM + rem] = o;
}

// ---------------------------------------------------------------------------
extern "C" void kernel_launch(void* const* d_in, const int* in_sizes, int n_in,
                              void* d_out, int out_size, void* d_ws, size_t ws_size,
                              hipStream_t stream) {
    const float* hs     = (const float*)d_in[0];
    // d_in[1] = cu_seqlens [0, 2048] — reference does no masking; unused.
    const float* cosb   = (const float*)d_in[2];
    const float* sinb   = (const float*)d_in[3];
    const float* w_qkv  = (const float*)d_in[4];
    const float* b_qkv  = (const float*)d_in[5];
    const float* w_proj = (const float*)d_in[6];
    const float* b_proj = (const float*)d_in[7];
    float* out = (float*)d_out;

    _Float16* hsb    = (_Float16*)d_ws;                       // 2048*1280
    _Float16* wqkvb  = hsb    + (long)SEQLEN * DIMM;          // 3840*1280
    _Float16* wprojb = wqkvb  + (long)QKV_N * DIMM;           // 1280*1280
    _Float16* qkv    = wprojb + (long)DIMM * DIMM;            // 2048*3840
    _Float16* Qh     = qkv    + (long)SEQLEN * QKV_N;         // 16*2048*80
    _Float16* Kh     = Qh     + (long)NHEADS * SEQLEN * HD;
    _Float16* Vtb    = Kh     + (long)NHEADS * SEQLEN * HD;   // 16*80*2048
    _Float16* attnb  = Vtb    + (long)NHEADS * HD * SEQLEN;   // 2048*1280

    // attention partials alias DEAD regions during attention:
    //   Ohat0 (z=0,1): hsb+wqkvb region (15.07 MB) — dead after QKV GEMM.
    //   Ohat1 (z=2,3): qkv region (15.73 MB) — dead after rope_repack_t.
    _Float16* Ohat0  = (_Float16*)d_ws;
    float*    LpartB = (float*)(Ohat0 + (long)2 * NHEADS * SEQLEN * HD);
    _Float16* Ohat1  = qkv;

    {
        const int ntot = (SEQLEN * DIMM + QKV_N * DIMM + DIMM * DIMM) / 4;
        cast_all<<<(ntot + 255) / 256, 256, 0, stream>>>(
            hs, w_qkv, w_proj, hsb, wqkvb, wprojb);
    }

    gemm_bt128<true><<<dim3(SEQLEN / 128, QKV_N / 128), 512, 0, stream>>>(
        hsb, wqkvb, b_qkv, qkv, SEQLEN, QKV_N, DIMM);

    rope_repack_t<<<dim3(SEQLEN / 64, NHEADS), 256, 0, stream>>>(
        qkv, cosb, sinb, Qh, Kh, Vtb);

    attn_kernel<<<dim3(SEQLEN / 256, NHEADS, NSPLIT), 512, 0, stream>>>(
        Qh, Kh, Vtb, Ohat0, Ohat1, LpartB);

    attn_combine<<<(SEQLEN * DIMM / 8 + 255) / 256, 256, 0, stream>>>(
        Ohat0, Ohat1, LpartB, attnb);

    gemm_bt64<false><<<dim3(SEQLEN / 64, DIMM / 128), 256, 0, stream>>>(
        attnb, wprojb, b_proj, out, SEQLEN, DIMM, DIMM);
}